// Round 5
// baseline (169.429 us; speedup 1.0000x reference)
//
#include <hip/hip_runtime.h>
#include <stdint.h>

#define BATCH 32768
#define DIM   512
#define KCLS  512

typedef __bf16    bf16x8 __attribute__((ext_vector_type(8)));
typedef float     f32x4  __attribute__((ext_vector_type(4)));
typedef float     f32x8  __attribute__((ext_vector_type(8)));
typedef uint16_t  u16x8  __attribute__((ext_vector_type(8)));

__device__ __forceinline__ uint16_t f2bf(float f) {
    // RTNE fp32 -> bf16
    uint32_t u = __float_as_uint(f);
    u += 0x7FFFu + ((u >> 16) & 1u);
    return (uint16_t)(u >> 16);
}

#define MFMA(a, b, c) __builtin_amdgcn_mfma_f32_16x16x32_bf16((a), (b), (c), 0, 0, 0)

// ---------------------------------------------------------------------------
// Prep: means (K x D fp32) -> bf16 pre-swizzled into MFMA B-fragment order.
// B-frag for mfma_f32_16x16x32_bf16: B[k = 8*(lane>>4)+j][n = lane&15].
// Bsw layout: index = (((c16*16 + ch)*64) + lane)*8, col = 16*c16 + (lane&15),
// k = 32*ch + 8*(lane>>4) + j.  Also computes inv_var/alpha/beta per class.
// ---------------------------------------------------------------------------
__global__ __launch_bounds__(256) void gmm_prep(
    const float* __restrict__ means,
    const float* __restrict__ log_vars,
    const float* __restrict__ log_weights,
    uint16_t* __restrict__ Bsw,
    float* __restrict__ invv_a,
    float* __restrict__ alpha_a,
    float* __restrict__ beta_a)
{
    const int k = blockIdx.x * 4 + (threadIdx.x >> 6);  // class index
    const int l = threadIdx.x & 63;                     // lane: elems 8l..8l+7

    const float* mrow = means + (size_t)k * DIM + l * 8;
    f32x4 v0 = *(const f32x4*)(mrow);
    f32x4 v1 = *(const f32x4*)(mrow + 4);

    u16x8 pk;
    pk[0] = f2bf(v0[0]); pk[1] = f2bf(v0[1]); pk[2] = f2bf(v0[2]); pk[3] = f2bf(v0[3]);
    pk[4] = f2bf(v1[0]); pk[5] = f2bf(v1[1]); pk[6] = f2bf(v1[2]); pk[7] = f2bf(v1[3]);

    const int c16 = k >> 4, r = k & 15, ch = l >> 2, hh = l & 3;
    *(u16x8*)(Bsw + ((((c16 * 16) + ch) * 64) + (hh * 16 + r)) * 8) = pk;

    float sq = v0[0]*v0[0] + v0[1]*v0[1] + v0[2]*v0[2] + v0[3]*v0[3]
             + v1[0]*v1[0] + v1[1]*v1[1] + v1[2]*v1[2] + v1[3]*v1[3];
    #pragma unroll
    for (int m = 1; m <= 32; m <<= 1) sq += __shfl_xor(sq, m);

    if (l == 0) {
        const float lv = log_vars[k];
        const float iv = __expf(-lv);
        invv_a[k]  = iv;
        alpha_a[k] = -0.5f * iv;
        beta_a[k]  = -0.5f * (sq * iv + (float)DIM * lv) + log_weights[k];
    }
}

// ---------------------------------------------------------------------------
// Main fused kernel, R8 = R4 geometry with x-staging FUSED into the K-loop.
// Model (calibrated R4-R7): R4's 47us = serial phases stage(10us,HBM) +
// Kloop(~15us,B-L2) + store(10us,HBM), x4/3 tail. R7 proved extra TLP does
// NOT help (occupancy 2x, slower) -> the fix is phase overlap, not waves.
// R8 changes vs R4 (register-neutral by design, cliff at ArchVGPR>106):
//   * x staged per chunk-pair DURING the K-loop: distance-2 prefetch
//     (xva/xvb, 16 VGPR) covers ~900cy HBM latency over ~2 pair bodies.
//   * B pipeline cut from Ba[8]+Bb[8] (64 VGPR) to single rotating Ba[8]
//     (32 VGPR), load-after-last-use: same ~14-16-MFMA load-use distance
//     as R4's double buffer. Pays for the xv regs. Live set ~92 < 106.
//   * 7 extra per-pair __syncthreads (vmcnt(0) drains) accepted: the 3
//     resident blocks/CU desync and cover each other's drains.
// Layouts, epilogue, prep identical to R4.
// (R4 bench attempt failed on infra — container died twice, no counters;
//  kernel re-audited: uniform barriers, disjoint LDS regions, correct
//  pipeline bookkeeping. Resubmitting unchanged.)
// ---------------------------------------------------------------------------
__global__ __launch_bounds__(256, 3) void gmm_main(
    const float* __restrict__ x,
    const uint16_t* __restrict__ Bsw,
    const float* __restrict__ invv_a,
    const float* __restrict__ alpha_a,
    const float* __restrict__ beta_a,
    float* __restrict__ out)
{
    __shared__ uint16_t As[16384];   // 32 KB: 32 rows x 512 k, A-frag order
    __shared__ float xsq_lds[32];
    __shared__ float pmax[4][32];
    __shared__ float psum[4][32];

    const int t    = threadIdx.x;
    const int w    = t >> 6;        // wave -> col group (128 cols)
    const int lane = t & 63;
    const int r16  = lane & 15;
    const int h    = lane >> 4;
    const int row0 = blockIdx.x * 32;

    // staging identity: thread t stages row sr, octet oin of each pair.
    // pair p covers k-octets o = 8p+oin -> chunk c = 2p+(oin>>2), hh = oin&3.
    const int sr = t >> 3, oin = t & 7;
    const int rt_s = sr >> 4, r16_s = sr & 15;
    const float* xr = x + (size_t)(row0 + sr) * DIM + 8 * oin;
    uint16_t* wslot = As + ((((oin >> 2) * 2 + rt_s) * 64) + (oin & 3) * 16 + r16_s) * 8;
    // per-pair stride in u16 units: delta_c = 2 -> 2*2*64*8 = 2048

    const uint16_t* bb = Bsw + (size_t)w * 65536 + (size_t)lane * 8;
    const uint16_t* ab = As + (size_t)lane * 8;     // LDS, frag base

    f32x4 acc[2][8];
    #pragma unroll
    for (int rt = 0; rt < 2; ++rt)
        #pragma unroll
        for (int ct = 0; ct < 8; ++ct)
            acc[rt][ct] = (f32x4){0.f, 0.f, 0.f, 0.f};

    // ---- prologue: issue L(0),L(1) + B chunk 0; write W(0); barrier ----
    f32x8 xva = *(const f32x8*)(xr);         // L(0)
    f32x8 xvb = *(const f32x8*)(xr + 64);    // L(1)
    bf16x8 Ba[8];
    #pragma unroll
    for (int ct = 0; ct < 8; ++ct) Ba[ct] = *(const bf16x8*)(bb + ct * 8192);

    float xsq_p = 0.f;
    {
        u16x8 pk;
        #pragma unroll
        for (int j = 0; j < 8; ++j) { xsq_p += xva[j] * xva[j]; pk[j] = f2bf(xva[j]); }
        *(u16x8*)wslot = pk;
    }
    __syncthreads();

    // ---- fused K-loop: 8 pairs; MFMA pair p, load L(p+2), write W(p+1) ----
    #pragma unroll
    for (int p = 0; p < 8; ++p) {
        // L(p+2): even pairs -> xva, odd pairs -> xvb (buffer freed by W(p))
        if (p < 6) {
            if ((p & 1) == 0) xva = *(const f32x8*)(xr + 64 * (p + 2));
            else              xvb = *(const f32x8*)(xr + 64 * (p + 2));
        }

        // A frags for both chunks of the pair (4x ds_read_b128)
        bf16x8 A00 = *(const bf16x8*)(ab + (2 * p) * 1024);
        bf16x8 A01 = *(const bf16x8*)(ab + (2 * p) * 1024 + 512);
        bf16x8 A10 = *(const bf16x8*)(ab + (2 * p) * 1024 + 1024);
        bf16x8 A11 = *(const bf16x8*)(ab + (2 * p) * 1024 + 1536);

        // even chunk c=2p: use Ba, reload Ba[ct] with chunk 2p+1 after last use
        #pragma unroll
        for (int ct = 0; ct < 8; ++ct) {
            acc[0][ct] = MFMA(A00, Ba[ct], acc[0][ct]);
            acc[1][ct] = MFMA(A01, Ba[ct], acc[1][ct]);
            Ba[ct] = *(const bf16x8*)(bb + ct * 8192 + (2 * p + 1) * 512);
        }
        // odd chunk c=2p+1: use Ba, reload with chunk 2p+2
        #pragma unroll
        for (int ct = 0; ct < 8; ++ct) {
            acc[0][ct] = MFMA(A10, Ba[ct], acc[0][ct]);
            acc[1][ct] = MFMA(A11, Ba[ct], acc[1][ct]);
            if (p < 7) Ba[ct] = *(const bf16x8*)(bb + ct * 8192 + (2 * p + 2) * 512);
        }

        // W(p+1): consume the buffer loaded one pair ago, write LDS, barrier
        if (p < 7) {
            const f32x8 v = ((p & 1) == 0) ? xvb : xva;
            u16x8 pk;
            #pragma unroll
            for (int j = 0; j < 8; ++j) { xsq_p += v[j] * v[j]; pk[j] = f2bf(v[j]); }
            *(u16x8*)(wslot + 2048 * (p + 1)) = pk;
            __syncthreads();
        }
    }

    // ---- xsq finalize (threads sharing a row differ in lane bits 0..2) ----
    xsq_p += __shfl_xor(xsq_p, 1);
    xsq_p += __shfl_xor(xsq_p, 2);
    xsq_p += __shfl_xor(xsq_p, 4);
    if (oin == 0) xsq_lds[sr] = xsq_p;
    __syncthreads();

    // ---- per-column affine params (L2-hot; after K-loop on purpose) ----
    float invv[8], alf[8], bet[8];
    #pragma unroll
    for (int ct = 0; ct < 8; ++ct) {
        const int col = 128 * w + 16 * ct + r16;
        invv[ct] = invv_a[col];
        alf[ct]  = alpha_a[col];
        bet[ct]  = beta_a[col];
    }
    float xsq[2][4];
    #pragma unroll
    for (int rt = 0; rt < 2; ++rt)
        #pragma unroll
        for (int reg = 0; reg < 4; ++reg)
            xsq[rt][reg] = xsq_lds[16 * rt + 4 * h + reg];

    // ---- logits + per-row max (C layout: col=lane&15, row=4*(lane>>4)+reg) ----
    float mr[2][4];
    #pragma unroll
    for (int rt = 0; rt < 2; ++rt) {
        #pragma unroll
        for (int reg = 0; reg < 4; ++reg) {
            float m = -1e30f;
            #pragma unroll
            for (int ct = 0; ct < 8; ++ct) {
                const float v = acc[rt][ct][reg] * invv[ct] + (alf[ct] * xsq[rt][reg] + bet[ct]);
                acc[rt][ct][reg] = v;
                m = fmaxf(m, v);
            }
            m = fmaxf(m, __shfl_xor(m, 1));
            m = fmaxf(m, __shfl_xor(m, 2));
            m = fmaxf(m, __shfl_xor(m, 4));
            m = fmaxf(m, __shfl_xor(m, 8));
            mr[rt][reg] = m;
        }
    }
    if (r16 == 0) {
        #pragma unroll
        for (int rt = 0; rt < 2; ++rt)
            #pragma unroll
            for (int reg = 0; reg < 4; ++reg)
                pmax[w][16 * rt + 4 * h + reg] = mr[rt][reg];
    }
    __syncthreads();

    // ---- exp + per-row sum ----
    float sr_[2][4];
    #pragma unroll
    for (int rt = 0; rt < 2; ++rt) {
        #pragma unroll
        for (int reg = 0; reg < 4; ++reg) {
            const int rl = 16 * rt + 4 * h + reg;
            const float m = fmaxf(fmaxf(pmax[0][rl], pmax[1][rl]),
                                  fmaxf(pmax[2][rl], pmax[3][rl]));
            float s = 0.f;
            #pragma unroll
            for (int ct = 0; ct < 8; ++ct) {
                const float e = __expf(acc[rt][ct][reg] - m);
                acc[rt][ct][reg] = e;
                s += e;
            }
            s += __shfl_xor(s, 1);
            s += __shfl_xor(s, 2);
            s += __shfl_xor(s, 4);
            s += __shfl_xor(s, 8);
            sr_[rt][reg] = s;
        }
    }
    if (r16 == 0) {
        #pragma unroll
        for (int rt = 0; rt < 2; ++rt)
            #pragma unroll
            for (int reg = 0; reg < 4; ++reg)
                psum[w][16 * rt + 4 * h + reg] = sr_[rt][reg];
    }
    __syncthreads();

    // ---- normalize + store ----
    #pragma unroll
    for (int rt = 0; rt < 2; ++rt) {
        #pragma unroll
        for (int reg = 0; reg < 4; ++reg) {
            const int rl = 16 * rt + 4 * h + reg;
            const float tot = (psum[0][rl] + psum[1][rl]) + (psum[2][rl] + psum[3][rl]);
            const float rinv = 1.0f / tot;
            float* orow = out + (size_t)(row0 + rl) * KCLS + 128 * w + r16;
            #pragma unroll
            for (int ct = 0; ct < 8; ++ct)
                orow[16 * ct] = acc[rt][ct][reg] * rinv;
        }
    }
}

extern "C" void kernel_launch(void* const* d_in, const int* in_sizes, int n_in,
                              void* d_out, int out_size, void* d_ws, size_t ws_size,
                              hipStream_t stream) {
    (void)in_sizes; (void)n_in; (void)out_size; (void)ws_size;
    const float* x           = (const float*)d_in[0];
    const float* means       = (const float*)d_in[1];
    const float* log_vars    = (const float*)d_in[2];
    const float* log_weights = (const float*)d_in[3];
    float* out = (float*)d_out;

    // ws: [0, 512KB) swizzled bf16 means; then inv_var/alpha/beta (512 f32 each)
    uint16_t* Bsw = (uint16_t*)d_ws;
    float* invv_a  = (float*)((char*)d_ws + (512u << 10));
    float* alpha_a = invv_a + KCLS;
    float* beta_a  = alpha_a + KCLS;

    gmm_prep<<<KCLS / 4, 256, 0, stream>>>(means, log_vars, log_weights,
                                           Bsw, invv_a, alpha_a, beta_a);
    gmm_main<<<BATCH / 32, 256, 0, stream>>>(x, Bsw, invv_a, alpha_a, beta_a, out);
}